// Round 7
// baseline (288541.919 us; speedup 1.0000x reference)
//
#include <hip/hip_runtime.h>
#include <hip/hip_fp16.h>
#include <math.h>

typedef unsigned int  uint32;
typedef unsigned short u16;

#define NWG 65          // 1 sequential WG + 64 helper WGs
#define NTH 1024        // 16 waves -> 4 waves/SIMD -> 128-VGPR budget (design target)

// workspace layout (bytes)
#define OFF_XP   1024u                        // xp buffer [256][768] f32 (b_ih + b_hh[r,z] folded)
#define OFF_XC   (OFF_XP + 256u*768u*4u)      // Xc / seq / Xr buffer [256][256] f32
#define OFF_D    (OFF_XC + 256u*256u*4u)      // dec_out row buffer [256][256] f32
#define OFF_Y1   (OFF_D  + 256u*256u*4u)      // y1 [128][512] f32

typedef _Float16 half2_t __attribute__((ext_vector_type(2)));

__device__ __forceinline__ float fdot2f(uint32 w, uint32 h, float acc) {
#if __has_builtin(__builtin_amdgcn_fdot2)
  return __builtin_amdgcn_fdot2(__builtin_bit_cast(half2_t, w),
                                __builtin_bit_cast(half2_t, h), acc, false);
#else
  half2_t a = __builtin_bit_cast(half2_t, w);
  half2_t b = __builtin_bit_cast(half2_t, h);
  return acc + (float)a[0]*(float)b[0] + (float)a[1]*(float)b[1];
#endif
}

__device__ __forceinline__ uint32 pack_h2(float x, float y) {
  _Float16 hx = (_Float16)x, hy = (_Float16)y;
  u16 ux = __builtin_bit_cast(u16, hx);
  u16 uy = __builtin_bit_cast(u16, hy);
  return (uint32)ux | ((uint32)uy << 16);
}

// pack 8 consecutive f32 -> uint4 of 4 packed f16-pairs
__device__ __forceinline__ uint4 pk4(const float* __restrict__ p) {
  return uint4{pack_h2(p[0],p[1]), pack_h2(p[2],p[3]),
               pack_h2(p[4],p[5]), pack_h2(p[6],p[7])};
}

__device__ __forceinline__ float sigm(float x) { return 1.0f/(1.0f + expf(-x)); }

// DPP lane-sum: v += v[src lane per quad_perm ctrl] (explicit per-lane sources)
template<int CTRL>
__device__ __forceinline__ float dppadd(float v) {
  int j = __builtin_amdgcn_mov_dpp(__builtin_bit_cast(int, v), CTRL, 0xf, 0xf, false);
  return v + __builtin_bit_cast(float, j);
}
// reduce across the 8 lanes of an octet (tid&7 = k-chunk); valid on all lanes.
// steps 1-2: quad_perm xor1 (0xB1), xor2 (0x4E); step 3: shfl_xor 4 (direction-proof).
#define ORED(a) { a = dppadd<0xB1>(a); a = dppadd<0x4E>(a); a += __shfl_xor(a, 4); }

// one uint4 of h (8 f16, k = q*32+J*8 ..+7) against all 6 owned rows
#define HSTEP(J, WA) { uint4 hh = hb4[(J)]; \
  ar0 = fdot2f(r0##WA.x, hh.x, ar0); ar0 = fdot2f(r0##WA.y, hh.y, ar0); \
  ar0 = fdot2f(r0##WA.z, hh.z, ar0); ar0 = fdot2f(r0##WA.w, hh.w, ar0); \
  az0 = fdot2f(z0##WA.x, hh.x, az0); az0 = fdot2f(z0##WA.y, hh.y, az0); \
  az0 = fdot2f(z0##WA.z, hh.z, az0); az0 = fdot2f(z0##WA.w, hh.w, az0); \
  an0 = fdot2f(n0##WA.x, hh.x, an0); an0 = fdot2f(n0##WA.y, hh.y, an0); \
  an0 = fdot2f(n0##WA.z, hh.z, an0); an0 = fdot2f(n0##WA.w, hh.w, an0); \
  ar1 = fdot2f(r1##WA.x, hh.x, ar1); ar1 = fdot2f(r1##WA.y, hh.y, ar1); \
  ar1 = fdot2f(r1##WA.z, hh.z, ar1); ar1 = fdot2f(r1##WA.w, hh.w, ar1); \
  az1 = fdot2f(z1##WA.x, hh.x, az1); az1 = fdot2f(z1##WA.y, hh.y, az1); \
  az1 = fdot2f(z1##WA.z, hh.z, az1); az1 = fdot2f(z1##WA.w, hh.w, az1); \
  an1 = fdot2f(n1##WA.x, hh.x, an1); an1 = fdot2f(n1##WA.y, hh.y, an1); \
  an1 = fdot2f(n1##WA.z, hh.z, an1); an1 = fdot2f(n1##WA.w, hh.w, an1); }

#define WROW(P)       uint4 P##a{}, P##b{}, P##c{}, P##d{};
#define LOADROW(P, R) { const float* _p = whh + (R)*256 + q*32; \
  P##a = pk4(_p); P##b = pk4(_p+8); P##c = pk4(_p+16); P##d = pk4(_p+24); }

// helper-WG input projection: xpo[t][o] = sum_k src[t][k]*wih[o][k] + bih[o] (+bhh[o] for o<512)
__device__ __forceinline__ void xp_gemm(
    const float* __restrict__ src, const float* __restrict__ wih,
    const float* __restrict__ bih, const float* __restrict__ bhh,
    float* __restrict__ xpo, int wgi, int tid, float (&XcL)[4][256])
{
  const int t0 = wgi * 4;
  XcL[tid >> 8][tid & 255] = src[t0 * 256 + tid];
  __syncthreads();
  if (tid < 768) {
    const int o = tid;
    const float* wr = wih + o * 256;
    float a0 = 0.f, a1 = 0.f, a2 = 0.f, a3 = 0.f;
#pragma unroll 4
    for (int k = 0; k < 256; ++k) {
      float w = wr[k];
      a0 += w * XcL[0][k]; a1 += w * XcL[1][k];
      a2 += w * XcL[2][k]; a3 += w * XcL[3][k];
    }
    float b = bih[o] + ((o < 512) ? bhh[o] : 0.f);
    xpo[(t0+0)*768+o] = a0+b; xpo[(t0+1)*768+o] = a1+b;
    xpo[(t0+2)*768+o] = a2+b; xpo[(t0+3)*768+o] = a3+b;
  }
  __syncthreads();
}

extern "C" __global__ void __launch_bounds__(NTH)
sed_kernel(const float* __restrict__ X,    const float* __restrict__ w1,
           const float* __restrict__ b1,   const float* __restrict__ w2,
           const float* __restrict__ b2,
           const float* __restrict__ ewih, const float* __restrict__ ewhh,
           const float* __restrict__ ebih, const float* __restrict__ ebhh,
           const float* __restrict__ dwih, const float* __restrict__ dwhh,
           const float* __restrict__ dbih, const float* __restrict__ dbhh,
           const float* __restrict__ fcw,  const float* __restrict__ fcb,
           float* __restrict__ out, unsigned char* __restrict__ ws)
{
  const int tid = threadIdx.x;
  const int wg  = blockIdx.x;
  uint32* bar_cnt = (uint32*)(ws);
  uint32* bar_rel = (uint32*)(ws + 128);
  float* xp = (float*)(ws + OFF_XP);
  float* Xc = (float*)(ws + OFF_XC);
  float* D  = (float*)(ws + OFF_D);
  float* y1 = (float*)(ws + OFF_Y1);

  __shared__ __align__(16) u16 h16d[2*256];   // double-buffered h (f16)
  __shared__ float XcL[4][256];
  __shared__ float hv[256], red[256], abuf[256], cbuf[256], pbuf[256];
  __shared__ float pbuf4[1024], cbuf4[1024];
  __shared__ float lbuf[26*8], la[32];

  unsigned round_ = 0;
  auto gbar = [&]() {
    __syncthreads();
    if (tid == 0) {
      unsigned old = __hip_atomic_fetch_add(bar_cnt, 1u, __ATOMIC_ACQ_REL,
                                            __HIP_MEMORY_SCOPE_AGENT);
      unsigned tgt = (round_ + 1u) * (unsigned)NWG;
      if (old + 1u == tgt)
        __hip_atomic_store(bar_rel, round_ + 1u, __ATOMIC_RELEASE,
                           __HIP_MEMORY_SCOPE_AGENT);
      while (__hip_atomic_load(bar_rel, __ATOMIC_ACQUIRE,
                               __HIP_MEMORY_SCOPE_AGENT) < round_ + 1u)
        __builtin_amdgcn_s_sleep(2);
    }
    round_ += 1u;
    __syncthreads();
  };

  const int u = tid >> 3;     // hidden-unit base: owns units u and u+128
  const int q = tid & 7;      // K-chunk (32 wide): k in [q*32, q*32+32)
  WROW(r0) WROW(z0) WROW(n0)  // 6 rows x 4 uint4 = 96 weight VGPRs
  WROW(r1) WROW(z1) WROW(n1)
  float bn0 = 0.f, bn1 = 0.f, hreg0 = 0.f, hreg1 = 0.f;

  auto loadW = [&](const float* __restrict__ whh, const float* __restrict__ bhh) {
    LOADROW(r0, u)        LOADROW(z0, 256 + u)  LOADROW(n0, 512 + u)
    LOADROW(r1, 128 + u)  LOADROW(z1, 384 + u)  LOADROW(n1, 640 + u)
    bn0 = bhh[512 + u]; bn1 = bhh[640 + u];
  };

  // 256 sequential GRU cells; one barrier per cell (double-buffered h).
  auto cells = [&](const float* __restrict__ xpb, float* __restrict__ dst,
                   bool relu) {
    int p = 0;
    const bool act = ((tid & 7) == 0);
    for (int t = 0; t < 256; ++t) {
      const float* xpt = xpb + t * 768;
      float xr0=0.f, xz0=0.f, xn0=0.f, xr1=0.f, xz1=0.f, xn1=0.f;
      if (act) {                       // prefetch (hidden under dots)
        xr0 = xpt[u];       xz0 = xpt[256 + u]; xn0 = xpt[512 + u];
        xr1 = xpt[128 + u]; xz1 = xpt[384 + u]; xn1 = xpt[640 + u];
      }
      const uint4* hb4 = (const uint4*)(h16d + p * 256) + q * 4;
      float ar0=0.f, az0=0.f, an0=0.f, ar1=0.f, az1=0.f, an1=0.f;
      HSTEP(0, a) HSTEP(1, b) HSTEP(2, c) HSTEP(3, d)   // 96 dot2
      ORED(ar0) ORED(az0) ORED(an0) ORED(ar1) ORED(az1) ORED(an1)
      if (act) {
        float r0v = sigm(xr0 + ar0);               // b_r/b_z folded into xp
        float z0v = sigm(xz0 + az0);
        float n0v = tanhf(xn0 + r0v * (an0 + bn0));
        float h0n = (1.0f - z0v) * n0v + z0v * hreg0; hreg0 = h0n;
        float r1v = sigm(xr1 + ar1);
        float z1v = sigm(xz1 + az1);
        float n1v = tanhf(xn1 + r1v * (an1 + bn1));
        float h1n = (1.0f - z1v) * n1v + z1v * hreg1; hreg1 = h1n;
        u16* hw = h16d + (p ^ 1) * 256;
        hw[u]       = __builtin_bit_cast(u16, (_Float16)h0n);
        hw[u + 128] = __builtin_bit_cast(u16, (_Float16)h1n);
        dst[t * 256 + u]       = relu ? fmaxf(h0n, 0.0f) : h0n;
        dst[t * 256 + u + 128] = relu ? fmaxf(h1n, 0.0f) : h1n;
      }
      __syncthreads();                 // writes visible; old-buf reads done
      p ^= 1;
    }
  };

  // ---- P0a: y1[j][c] = w1[j]*x[c] + b1[j]   [128][512]
  for (int idx = wg * NTH + tid; idx < 128 * 512; idx += NWG * NTH) {
    int j = idx >> 9, c = idx & 511;
    y1[idx] = w1[j] * X[c] + b1[j];
  }
  gbar();

  // ---- P0b: seq[t][d] = y2[d][2t] (only even cols of y2 needed)
  for (int idx = wg * NTH + tid; idx < 256 * 256; idx += NWG * NTH) {
    int d = idx & 255, t = idx >> 8;
    const float* w2r = w2 + d * 128;
    float acc = b2[d];
#pragma unroll 4
    for (int j = 0; j < 128; ++j) acc += w2r[j] * y1[j * 512 + 2 * t];
    Xc[t * 256 + d] = acc;
  }
  gbar();

  // ---- P0c: helpers xp_enc = seq @ ewih^T + eb ; WG0 loads enc W_hh regs
  if (wg == 0) loadW(ewhh, ebhh);
  else         xp_gemm(Xc, ewih, ebih, ebhh, xp, wg - 1, tid, XcL);
  gbar();

  // ---- P1: encoder (256 cells), writes relu(h) into Xc (=Xr)
  if (wg == 0) {
    if (tid < 256) h16d[tid] = 0;
    hreg0 = 0.f; hreg1 = 0.f;
    __syncthreads();
    cells(xp, Xc, true);
  }
  gbar();

  // ---- P2: helpers xp^0 = Xr @ dwih^T + db ; WG0 loads dec W_hh regs
  if (wg == 0) loadW(dwhh, dbhh);
  else         xp_gemm(Xc, dwih, dbih, dbhh, xp, wg - 1, tid, XcL);
  gbar();

  // ---- decoder: 256 outer rows
  for (int k = 0; k < 256; ++k) {
    // phase 1: WG0 runs the 256 sequential cells of row k (h carries across rows)
    if (wg == 0) cells(xp, D, false);
    gbar();

    // phase 2: helpers build xp^{k+1} from D; WG0 does attention + output row k
    if (wg == 0) {
      if (tid < 256) hv[tid] = D[255 * 256 + tid];   // h_new vector
      __syncthreads();
      // s_t = D[t,:]·h_new  (4-way split per t)
      {
        int tt = tid & 255, qq = tid >> 8;
        const float* dr = D + tt * 256 + qq * 64;
        const float* hp = hv + qq * 64;
        float pP = 0.f;
#pragma unroll 4
        for (int e = 0; e < 64; ++e) pP += dr[e] * hp[e];
        pbuf4[qq * 256 + tt] = pP;
      }
      __syncthreads();
      if (tid < 256) {
        float s = pbuf4[tid] + pbuf4[256+tid] + pbuf4[512+tid] + pbuf4[768+tid];
        pbuf[tid] = s; red[tid] = s;
      }
      __syncthreads();
      for (int st = 128; st > 0; st >>= 1) {
        if (tid < st) red[tid] = fmaxf(red[tid], red[tid + st]);
        __syncthreads();
      }
      float m = red[0];
      __syncthreads();
      if (tid < 256) { float e = expf(pbuf[tid] - m); abuf[tid] = e; red[tid] = e; }
      __syncthreads();
      for (int st = 128; st > 0; st >>= 1) {
        if (tid < st) red[tid] += red[tid + st];
        __syncthreads();
      }
      float inv = 1.0f / red[0];
      __syncthreads();
      if (tid < 256) abuf[tid] *= inv;
      __syncthreads();
      // c_i = a[0]*D[0,i] + sum_{t=1..255} a[t-1]*D[t,i]   (4-way split over t)
      {
        int ii = tid & 255, qq = tid >> 8;
        float acc = (qq == 0) ? abuf[0] * D[ii] : 0.f;
        int t2 = (qq == 0) ? 1 : qq * 64;
        int tend = qq * 64 + 64;
        for (; t2 < tend; ++t2) acc += abuf[t2 - 1] * D[t2 * 256 + ii];
        cbuf4[qq * 256 + ii] = acc;
      }
      __syncthreads();
      if (tid < 256)
        cbuf[tid] = cbuf4[tid] + cbuf4[256+tid] + cbuf4[512+tid] + cbuf4[768+tid];
      __syncthreads();
      // logits: fc_w @ [h_new, c] + fc_b  (26 outputs, 8 partials each)
      if (tid < 26 * 8) {
        int j = tid >> 3, sgm = tid & 7;
        const float* fr   = fcw + j * 512 + sgm * 64;
        const float* vsrc = (sgm < 4) ? (hv + sgm * 64) : (cbuf + (sgm - 4) * 64);
        float pP = 0.f;
#pragma unroll 4
        for (int e = 0; e < 64; ++e) pP += fr[e] * vsrc[e];
        lbuf[tid] = pP;
      }
      __syncthreads();
      if (tid < 26) {
        float lgt = fcb[tid];
#pragma unroll
        for (int s = 0; s < 8; ++s) lgt += lbuf[tid * 8 + s];
        la[tid] = lgt;
      }
      __syncthreads();
      if (tid == 0) {
        float m2 = la[0];
        for (int j = 1; j < 26; ++j) m2 = fmaxf(m2, la[j]);
        float sm = 0.f;
        for (int j = 0; j < 26; ++j) { float e = expf(la[j] - m2); la[j] = e; sm += e; }
        float ii = 1.0f / sm;
        for (int j = 0; j < 26; ++j) la[j] *= ii;
      }
      __syncthreads();
      if (tid < 26) out[k * 26 + tid] = la[tid];
      __syncthreads();
    } else if (k < 255) {
      xp_gemm(D, dwih, dbih, dbhh, xp, wg - 1, tid, XcL);
    }
    gbar();
  }
}

extern "C" void kernel_launch(void* const* d_in, const int* in_sizes, int n_in,
                              void* d_out, int out_size, void* d_ws, size_t ws_size,
                              hipStream_t stream) {
  (void)in_sizes; (void)n_in; (void)out_size; (void)ws_size;
  // zero the grid-barrier counters (ws is poisoned 0xAA before every launch)
  hipMemsetAsync(d_ws, 0, 1024, stream);
  sed_kernel<<<NWG, NTH, 0, stream>>>(
      (const float*)d_in[0],  (const float*)d_in[1],  (const float*)d_in[2],
      (const float*)d_in[3],  (const float*)d_in[4],  (const float*)d_in[5],
      (const float*)d_in[6],  (const float*)d_in[7],  (const float*)d_in[8],
      (const float*)d_in[9],  (const float*)d_in[10], (const float*)d_in[11],
      (const float*)d_in[12], (const float*)d_in[13], (const float*)d_in[14],
      (float*)d_out, (unsigned char*)d_ws);
}

// Round 8
// 96323.151 us; speedup vs baseline: 2.9956x; 2.9956x over previous
//
#include <hip/hip_runtime.h>
#include <hip/hip_fp16.h>
#include <math.h>

typedef unsigned int  uint32;
typedef unsigned short u16;

#define NWG 65          // 1 sequential WG + 64 helper WGs
#define NTH 512

// workspace layout (bytes)
#define OFF_XP   1024u                        // xp buffer [256][768] f32
#define OFF_XC   (OFF_XP + 256u*768u*4u)      // Xc / seq / Xr buffer [256][256] f32
#define OFF_D    (OFF_XC + 256u*256u*4u)      // dec_out row buffer [256][256] f32
#define OFF_Y1   (OFF_D  + 256u*256u*4u)      // y1 [128][512] f32

// Static LDS sized > 80 KiB so only ONE block fits per CU (160 KiB pool):
// occupancy -> 8 waves/CU -> 2 waves/SIMD -> 256-VGPR RA budget.
#define SMEM_BYTES 86016

typedef _Float16 half2_t __attribute__((ext_vector_type(2)));

__device__ __forceinline__ float fdot2f(uint32 w, uint32 h, float acc) {
#if __has_builtin(__builtin_amdgcn_fdot2)
  return __builtin_amdgcn_fdot2(__builtin_bit_cast(half2_t, w),
                                __builtin_bit_cast(half2_t, h), acc, false);
#else
  half2_t a = __builtin_bit_cast(half2_t, w);
  half2_t b = __builtin_bit_cast(half2_t, h);
  return acc + (float)a[0]*(float)b[0] + (float)a[1]*(float)b[1];
#endif
}

__device__ __forceinline__ uint32 pack_h2(float x, float y) {
  _Float16 hx = (_Float16)x, hy = (_Float16)y;
  u16 ux = __builtin_bit_cast(u16, hx);
  u16 uy = __builtin_bit_cast(u16, hy);
  return (uint32)ux | ((uint32)uy << 16);
}

// pack 8 consecutive f32 -> uint4 of 4 packed f16-pairs
__device__ __forceinline__ uint4 pk4(const float* __restrict__ p) {
  return uint4{pack_h2(p[0],p[1]), pack_h2(p[2],p[3]),
               pack_h2(p[4],p[5]), pack_h2(p[6],p[7])};
}

__device__ __forceinline__ float sigm(float x) { return 1.0f/(1.0f + expf(-x)); }

// ---- 48 named uint4 weight registers per lane (192 VGPRs), macro-generated
#define REP32(M) M(0) M(1) M(2) M(3) M(4) M(5) M(6) M(7) M(8) M(9) M(10) M(11) \
  M(12) M(13) M(14) M(15) M(16) M(17) M(18) M(19) M(20) M(21) M(22) M(23) \
  M(24) M(25) M(26) M(27) M(28) M(29) M(30) M(31)
#define REP16(M) M(0) M(1) M(2) M(3) M(4) M(5) M(6) M(7) M(8) M(9) M(10) M(11) \
  M(12) M(13) M(14) M(15)

#define DECLF(j) uint4 F##j{};
#define DECLN(j) uint4 N##j{};
#define LDF(j)   F##j = pk4(wr + (j)*8);
#define LDN(j)   N##j = pk4(wn + (j)*8);

#define FD(j,hp) a0=fdot2f(F##j.x,hp.x,a0); a1=fdot2f(F##j.y,hp.y,a1); \
                 a0=fdot2f(F##j.z,hp.z,a0); a1=fdot2f(F##j.w,hp.w,a1);
#define ND(n,hp) b0=fdot2f(N##n.x,hp.x,b0); b1=fdot2f(N##n.y,hp.y,b1); \
                 b0=fdot2f(N##n.z,hp.z,b0); b1=fdot2f(N##n.w,hp.w,b1);
#define SF(j)    { uint4 hp = h4[j]; FD(j,hp) }
#define SFH(j,n) { uint4 hp = h4[j]; FD(j,hp) ND(n,hp) }

// helper-WG input projection: xpo[t][o] = sum_k src[t][k]*wih[o][k] + bih[o]
__device__ __forceinline__ void xp_gemm(
    const float* __restrict__ src, const float* __restrict__ wih,
    const float* __restrict__ bih, float* __restrict__ xpo,
    int wgi, int tid, float (*XcL)[256])
{
  const int t0 = wgi * 4;
  for (int r = tid; r < 1024; r += NTH) XcL[r >> 8][r & 255] = src[t0 * 256 + r];
  __syncthreads();
  for (int o = tid; o < 768; o += NTH) {
    const float* wr = wih + o * 256;
    float a0 = 0.f, a1 = 0.f, a2 = 0.f, a3 = 0.f;
#pragma unroll 4
    for (int k = 0; k < 256; ++k) {
      float w = wr[k];
      a0 += w * XcL[0][k]; a1 += w * XcL[1][k];
      a2 += w * XcL[2][k]; a3 += w * XcL[3][k];
    }
    float b = bih[o];
    xpo[(t0+0)*768+o] = a0+b; xpo[(t0+1)*768+o] = a1+b;
    xpo[(t0+2)*768+o] = a2+b; xpo[(t0+3)*768+o] = a3+b;
  }
  __syncthreads();
}

extern "C" __global__ void __launch_bounds__(NTH)
sed_kernel(const float* __restrict__ X,    const float* __restrict__ w1,
           const float* __restrict__ b1,   const float* __restrict__ w2,
           const float* __restrict__ b2,
           const float* __restrict__ ewih, const float* __restrict__ ewhh,
           const float* __restrict__ ebih, const float* __restrict__ ebhh,
           const float* __restrict__ dwih, const float* __restrict__ dwhh,
           const float* __restrict__ dbih, const float* __restrict__ dbhh,
           const float* __restrict__ fcw,  const float* __restrict__ fcb,
           float* __restrict__ out, unsigned char* __restrict__ ws)
{
  const int tid = threadIdx.x;
  const int wg  = blockIdx.x;
  uint32* bar_cnt = (uint32*)(ws);
  uint32* bar_rel = (uint32*)(ws + 128);
  float* xp = (float*)(ws + OFF_XP);
  float* Xc = (float*)(ws + OFF_XC);
  float* D  = (float*)(ws + OFF_D);
  float* y1 = (float*)(ws + OFF_Y1);

  // one big static LDS block (>80 KiB => 1 block/CU => 256-VGPR budget)
  __shared__ __align__(16) unsigned char SMEM[SMEM_BYTES];
  u16*   h16s = (u16*)SMEM;                         // 512 B
  float* zbuf = (float*)(SMEM + 512);               // 1 KB
  float* nbuf = (float*)(SMEM + 1536);              // 1 KB
  float (*XcL)[256] = (float(*)[256])(SMEM + 2560); // 4 KB
  float* hv   = (float*)(SMEM + 6656);              // 1 KB
  float* red  = (float*)(SMEM + 7680);              // 1 KB
  float* abuf = (float*)(SMEM + 8704);              // 1 KB
  float* cbuf = (float*)(SMEM + 9728);              // 1 KB
  float* pbuf = (float*)(SMEM + 10752);             // 2 KB (512 f)
  float* lbuf = (float*)(SMEM + 12800);             // 832 B
  float* la   = (float*)(SMEM + 13632);             // 128 B

  unsigned round_ = 0;
  auto gbar = [&]() {
    __syncthreads();
    if (tid == 0) {
      unsigned old = __hip_atomic_fetch_add(bar_cnt, 1u, __ATOMIC_ACQ_REL,
                                            __HIP_MEMORY_SCOPE_AGENT);
      unsigned tgt = (round_ + 1u) * (unsigned)NWG;
      if (old + 1u == tgt)
        __hip_atomic_store(bar_rel, round_ + 1u, __ATOMIC_RELEASE,
                           __HIP_MEMORY_SCOPE_AGENT);
      while (__hip_atomic_load(bar_rel, __ATOMIC_ACQUIRE,
                               __HIP_MEMORY_SCOPE_AGENT) < round_ + 1u)
        __builtin_amdgcn_s_sleep(2);
    }
    round_ += 1u;
    __syncthreads();
  };

  const int i   = tid & 255;
  const int cls = tid >> 8;        // wave-uniform (waves 0-3: cls0, 4-7: cls1)
  REP32(DECLF)                     // full gate row (r_i or z_i): 32 uint4
  REP16(DECLN)                     // n_i half row: 16 uint4
  float bfull = 0.f, bhalfn = 0.f, h_reg = 0.f;

  // lane (cls=0,i): rows r_i + n_i[0:128];  lane (cls=1,i): z_i + n_i[128:256]
  auto loadW = [&](const float* __restrict__ whh, const float* __restrict__ bhh) {
    const int rfull = (cls == 0) ? i : (256 + i);
    const float* wr = whh + rfull * 256;
    REP32(LDF)
    const float* wn = whh + (512 + i) * 256 + cls * 128;
    REP16(LDN)
    bfull  = bhh[rfull];
    bhalfn = (cls == 0) ? bhh[512 + i] : 0.0f;
  };

  // 256 sequential GRU cells; 2 barriers/cell; h broadcast via LDS (f16).
  auto cells = [&](const float* __restrict__ xpb, float* __restrict__ dst,
                   bool relu) {
    const uint4* h4 = (const uint4*)h16s;
    for (int t = 0; t < 256; ++t) {
      const float* xpt = xpb + t * 768;
      float xA = (cls == 0) ? xpt[i] : xpt[256 + i];   // xr | xz
      float xB = (cls == 0) ? xpt[512 + i] : 0.0f;     // xn (cls0 only)
      float a0 = 0.f, a1 = 0.f, b0 = 0.f, b1 = 0.f;
      if (cls == 0) {   // full row k 0..255; half row k 0..127 (reuse hp)
        SFH(0,0)  SFH(1,1)  SFH(2,2)   SFH(3,3)   SFH(4,4)   SFH(5,5)
        SFH(6,6)  SFH(7,7)  SFH(8,8)   SFH(9,9)   SFH(10,10) SFH(11,11)
        SFH(12,12) SFH(13,13) SFH(14,14) SFH(15,15)
        SF(16) SF(17) SF(18) SF(19) SF(20) SF(21) SF(22) SF(23)
        SF(24) SF(25) SF(26) SF(27) SF(28) SF(29) SF(30) SF(31)
      } else {          // full row k 0..255; half row k 128..255 (reuse hp)
        SF(0) SF(1) SF(2) SF(3) SF(4) SF(5) SF(6) SF(7)
        SF(8) SF(9) SF(10) SF(11) SF(12) SF(13) SF(14) SF(15)
        SFH(16,0)  SFH(17,1)  SFH(18,2)  SFH(19,3)  SFH(20,4)  SFH(21,5)
        SFH(22,6)  SFH(23,7)  SFH(24,8)  SFH(25,9)  SFH(26,10) SFH(27,11)
        SFH(28,12) SFH(29,13) SFH(30,14) SFH(31,15)
      }
      float gfull = a0 + a1 + bfull;   // Wr·h+br (cls0) | Wz·h+bz (cls1)
      float ghalf = b0 + b1;           // partial Wn·h
      if (cls) {
        zbuf[i] = sigm(xA + gfull);    // z_i
        nbuf[i] = ghalf;               // n partial (k=128..255)
      }
      __syncthreads();
      if (!cls) {
        float r    = sigm(xA + gfull);
        float hn   = ghalf + nbuf[i] + bhalfn;           // Wn·h + b_hh_n
        float n    = tanhf(xB + r * hn);
        float z    = zbuf[i];
        float hnew = (1.0f - z) * n + z * h_reg;
        h_reg = hnew;
        h16s[i] = __builtin_bit_cast(u16, (_Float16)hnew);
        dst[t * 256 + i] = relu ? fmaxf(hnew, 0.0f) : hnew;
      }
      __syncthreads();
    }
  };

  // ---- P0a: y1[j][c] = w1[j]*x[c] + b1[j]   [128][512]
  for (int idx = wg * NTH + tid; idx < 128 * 512; idx += NWG * NTH) {
    int j = idx >> 9, c = idx & 511;
    y1[idx] = w1[j] * X[c] + b1[j];
  }
  gbar();

  // ---- P0b: seq[t][d] = y2[d][2t] (only even cols of y2 needed)
  for (int idx = wg * NTH + tid; idx < 256 * 256; idx += NWG * NTH) {
    int d = idx & 255, t = idx >> 8;
    const float* w2r = w2 + d * 128;
    float acc = b2[d];
#pragma unroll 4
    for (int j = 0; j < 128; ++j) acc += w2r[j] * y1[j * 512 + 2 * t];
    Xc[t * 256 + d] = acc;
  }
  gbar();

  // ---- P0c: helpers xp_enc = seq @ ewih^T + ebih ; WG0 loads enc W_hh regs
  if (wg == 0) loadW(ewhh, ebhh);
  else         xp_gemm(Xc, ewih, ebih, xp, wg - 1, tid, XcL);
  gbar();

  // ---- P1: encoder (256 cells), writes relu(h) into Xc (=Xr)
  if (wg == 0) {
    if (tid < 256) h16s[tid] = 0;
    h_reg = 0.f;
    __syncthreads();
    cells(xp, Xc, true);
  }
  gbar();

  // ---- P2: helpers xp^0 = Xr @ dwih^T + dbih ; WG0 loads dec W_hh regs
  if (wg == 0) loadW(dwhh, dbhh);
  else         xp_gemm(Xc, dwih, dbih, xp, wg - 1, tid, XcL);
  gbar();

  // ---- decoder: 256 outer rows
  for (int k = 0; k < 256; ++k) {
    // phase 1: WG0 runs the 256 sequential cells of row k (h carries across rows)
    if (wg == 0) cells(xp, D, false);
    gbar();

    // phase 2: helpers build xp^{k+1} from D; WG0 does attention + output row k
    if (wg == 0) {
      if (tid < 256) hv[tid] = D[255 * 256 + tid];   // h_new vector
      __syncthreads();
      // s_t = D[t,:]·h_new  (split each dot across 2 threads)
      {
        int t = tid & 255, hh = tid >> 8;
        const float* dr  = D + t * 256 + hh * 128;
        const float* hvp = hv + hh * 128;
        float p = 0.f;
#pragma unroll 4
        for (int q = 0; q < 128; ++q) p += dr[q] * hvp[q];
        pbuf[hh * 256 + t] = p;
      }
      __syncthreads();
      if (tid < 256) { float s = pbuf[tid] + pbuf[256 + tid]; pbuf[tid] = s; red[tid] = s; }
      __syncthreads();
      for (int st = 128; st > 0; st >>= 1) {
        if (tid < st) red[tid] = fmaxf(red[tid], red[tid + st]);
        __syncthreads();
      }
      float m = red[0];
      __syncthreads();
      if (tid < 256) { float e = expf(pbuf[tid] - m); abuf[tid] = e; red[tid] = e; }
      __syncthreads();
      for (int st = 128; st > 0; st >>= 1) {
        if (tid < st) red[tid] += red[tid + st];
        __syncthreads();
      }
      float inv = 1.0f / red[0];
      __syncthreads();
      if (tid < 256) abuf[tid] *= inv;
      __syncthreads();
      // c[i] = a[0]*D[0,i] + sum_{t=1..255} a[t-1]*D[t,i]
      if (tid < 256) {
        float acc = abuf[0] * D[tid];
        for (int t = 1; t < 256; ++t) acc += abuf[t - 1] * D[t * 256 + tid];
        cbuf[tid] = acc;
      }
      __syncthreads();
      // logits: fc_w @ [h_new, c] + fc_b  (26 outputs, 8 partials each)
      if (tid < 26 * 8) {
        int j = tid >> 3, sgm = tid & 7;
        const float* fr   = fcw + j * 512 + sgm * 64;
        const float* vsrc = (sgm < 4) ? (hv + sgm * 64) : (cbuf + (sgm - 4) * 64);
        float p = 0.f;
#pragma unroll 4
        for (int q = 0; q < 64; ++q) p += fr[q] * vsrc[q];
        lbuf[tid] = p;
      }
      __syncthreads();
      if (tid < 26) {
        float l = fcb[tid];
#pragma unroll
        for (int s = 0; s < 8; ++s) l += lbuf[tid * 8 + s];
        la[tid] = l;
      }
      __syncthreads();
      if (tid == 0) {
        float m2 = la[0];
        for (int j = 1; j < 26; ++j) m2 = fmaxf(m2, la[j]);
        float sm = 0.f;
        for (int j = 0; j < 26; ++j) { float e = expf(la[j] - m2); la[j] = e; sm += e; }
        float ii = 1.0f / sm;
        for (int j = 0; j < 26; ++j) la[j] *= ii;
      }
      __syncthreads();
      if (tid < 26) out[k * 26 + tid] = la[tid];
      __syncthreads();
    } else if (k < 255) {
      xp_gemm(D, dwih, dbih, xp, wg - 1, tid, XcL);
    }
    gbar();
  }
}

extern "C" void kernel_launch(void* const* d_in, const int* in_sizes, int n_in,
                              void* d_out, int out_size, void* d_ws, size_t ws_size,
                              hipStream_t stream) {
  (void)in_sizes; (void)n_in; (void)out_size; (void)ws_size;
  // zero the grid-barrier counters (ws is poisoned 0xAA before every launch)
  hipMemsetAsync(d_ws, 0, 1024, stream);
  sed_kernel<<<NWG, NTH, 0, stream>>>(
      (const float*)d_in[0],  (const float*)d_in[1],  (const float*)d_in[2],
      (const float*)d_in[3],  (const float*)d_in[4],  (const float*)d_in[5],
      (const float*)d_in[6],  (const float*)d_in[7],  (const float*)d_in[8],
      (const float*)d_in[9],  (const float*)d_in[10], (const float*)d_in[11],
      (const float*)d_in[12], (const float*)d_in[13], (const float*)d_in[14],
      (float*)d_out, (unsigned char*)d_ws);
}